// Round 1
// baseline (3660.953 us; speedup 1.0000x reference)
//
#include <hip/hip_runtime.h>
#include <hip/hip_bf16.h>
#include <math.h>

#define S_LEN 2048
#define DK    64
#define TQ    8      // query rows per block
#define NT    256    // threads per block
#define BH    64     // B*H
#define SCALE 0.125f // 1/sqrt(64)

__global__ __launch_bounds__(NT) void attn_fwd(const float* __restrict__ Q,
                                               const float* __restrict__ K,
                                               const float* __restrict__ V,
                                               float* __restrict__ Out,
                                               float* __restrict__ W) {
  __shared__ float4 sQ4[TQ][DK / 4];          // 2 KB
  __shared__ __hip_bfloat16 wS[S_LEN][TQ];    // 32 KB, [k][r] so one b128 = 8 rows
  __shared__ float pOut[4][TQ][DK];           // 8 KB
  __shared__ float redm[4], reds[4];

  const int t    = threadIdx.x;
  const int lane = t & 63;
  const int wid  = t >> 6;
  const int bh   = blockIdx.y;
  const int q0   = blockIdx.x * TQ;

  const float* Qb = Q + (size_t)bh * S_LEN * DK;
  const float* Kb = K + (size_t)bh * S_LEN * DK;
  const float* Vb = V + (size_t)bh * S_LEN * DK;

  // ---- load Q tile (8x64 fp32) into LDS as float4 ----
  for (int i = t; i < TQ * (DK / 4); i += NT) {
    int r = i / (DK / 4), c = i % (DK / 4);
    sQ4[r][c] = reinterpret_cast<const float4*>(Qb + (size_t)(q0 + r) * DK)[c];
  }
  __syncthreads();

  const int kmax = q0 + TQ;                 // keys beyond this are masked for all rows
  const int jcnt = (kmax + NT - 1) / NT;    // 256-key chunks actually needed (causal skip)

  // ---- scores: thread t owns keys k = t + 256*j ----
  float sc[TQ][8];
#pragma unroll
  for (int r = 0; r < TQ; ++r)
#pragma unroll
    for (int j = 0; j < 8; ++j) sc[r][j] = 0.f;

#pragma unroll
  for (int j = 0; j < 8; ++j) {
    if (j < jcnt) {                         // block-uniform branch
      const int k = t + NT * j;
      const float4* kp = reinterpret_cast<const float4*>(Kb + (size_t)k * DK);
#pragma unroll
      for (int dc = 0; dc < 4; ++dc) {
        float4 k0 = kp[dc * 4 + 0], k1 = kp[dc * 4 + 1];
        float4 k2 = kp[dc * 4 + 2], k3 = kp[dc * 4 + 3];
#pragma unroll
        for (int r = 0; r < TQ; ++r) {
          float4 qa = sQ4[r][dc * 4 + 0], qb = sQ4[r][dc * 4 + 1];
          float4 qc = sQ4[r][dc * 4 + 2], qd = sQ4[r][dc * 4 + 3];
          sc[r][j] += k0.x * qa.x + k0.y * qa.y + k0.z * qa.z + k0.w * qa.w
                    + k1.x * qb.x + k1.y * qb.y + k1.z * qb.z + k1.w * qb.w
                    + k2.x * qc.x + k2.y * qc.y + k2.z * qc.z + k2.w * qc.w
                    + k3.x * qd.x + k3.y * qd.y + k3.z * qd.z + k3.w * qd.w;
        }
      }
    }
  }

  // ---- per-row softmax + weights write ----
  float* Wbase = W + (size_t)bh * S_LEN * S_LEN;
#pragma unroll 1
  for (int r = 0; r < TQ; ++r) {
    const int row = q0 + r;
    float m = -INFINITY;
#pragma unroll
    for (int j = 0; j < 8; ++j) {
      int k = t + NT * j;
      float s = (k <= row) ? sc[r][j] * SCALE : -INFINITY;  // j>=jcnt auto-masked (k>row)
      sc[r][j] = s;
      m = fmaxf(m, s);
    }
#pragma unroll
    for (int off = 32; off > 0; off >>= 1) m = fmaxf(m, __shfl_down(m, off, 64));
    if (lane == 0) redm[wid] = m;
    __syncthreads();
    const float M = fmaxf(fmaxf(redm[0], redm[1]), fmaxf(redm[2], redm[3]));

    float ssum = 0.f;
#pragma unroll
    for (int j = 0; j < 8; ++j) {
      float e = __expf(sc[r][j] - M);   // exp(-inf)=0
      sc[r][j] = e;
      ssum += e;
    }
#pragma unroll
    for (int off = 32; off > 0; off >>= 1) ssum += __shfl_down(ssum, off, 64);
    if (lane == 0) reds[wid] = ssum;
    __syncthreads();
    const float inv = 1.f / (reds[0] + reds[1] + reds[2] + reds[3]);

    float* Wrow = Wbase + (size_t)row * S_LEN;
#pragma unroll
    for (int j = 0; j < 8; ++j) {
      int k = t + NT * j;
      float w = sc[r][j] * inv;         // covers all 2048 cols incl. zeros
      Wrow[k] = w;
      wS[k][r] = __float2bfloat16(w);
    }
  }
  __syncthreads();

  // ---- PV: wave w handles k = w (mod 4), lane = d ----
  const int d = lane, c = wid;
  float acc[TQ];
#pragma unroll
  for (int r = 0; r < TQ; ++r) acc[r] = 0.f;
  const int klim = (kmax < S_LEN) ? kmax : S_LEN;
  for (int k = c; k < klim; k += 4) {
    float v = Vb[(size_t)k * DK + d];                       // coalesced 256B/wave
    uint4 u = *reinterpret_cast<const uint4*>(&wS[k][0]);   // broadcast b128: 8 rows
    acc[0] += __uint_as_float(u.x << 16) * v;
    acc[1] += __uint_as_float(u.x & 0xffff0000u) * v;
    acc[2] += __uint_as_float(u.y << 16) * v;
    acc[3] += __uint_as_float(u.y & 0xffff0000u) * v;
    acc[4] += __uint_as_float(u.z << 16) * v;
    acc[5] += __uint_as_float(u.z & 0xffff0000u) * v;
    acc[6] += __uint_as_float(u.w << 16) * v;
    acc[7] += __uint_as_float(u.w & 0xffff0000u) * v;
  }
#pragma unroll
  for (int r = 0; r < TQ; ++r) pOut[c][r][d] = acc[r];
  __syncthreads();

  float* Ob = Out + ((size_t)bh * S_LEN + q0) * DK;
  for (int i = t; i < TQ * DK; i += NT) {
    int r = i >> 6, dd = i & 63;
    Ob[(size_t)r * DK + dd] =
        pOut[0][r][dd] + pOut[1][r][dd] + pOut[2][r][dd] + pOut[3][r][dd];
  }
}

extern "C" void kernel_launch(void* const* d_in, const int* in_sizes, int n_in,
                              void* d_out, int out_size, void* d_ws, size_t ws_size,
                              hipStream_t stream) {
  const float* Q = (const float*)d_in[0];
  const float* K = (const float*)d_in[1];
  const float* V = (const float*)d_in[2];
  // d_in[3] is the causal tril mask; handled analytically as k <= q.
  float* Out = (float*)d_out;
  float* W   = Out + (size_t)BH * S_LEN * DK;  // out first, then weights
  dim3 grid(S_LEN / TQ, BH);
  attn_fwd<<<grid, NT, 0, stream>>>(Q, K, V, Out, W);
}